// Round 2
// baseline (115.107 us; speedup 1.0000x reference)
//
#include <hip/hip_runtime.h>

#pragma clang fp contract(off)

#define Z0f   10.0f
#define EPSf  1e-6f
#define APER2 400.0f   // (DIAMETER/2)^2 = 20^2

__global__ __launch_bounds__(256) void refract_kernel(
    const float* __restrict__ P,
    const float* __restrict__ V,
    const float* __restrict__ Rp,
    const float* __restrict__ n1p,
    const float* __restrict__ n2p,
    float* __restrict__ out,
    int nQuads)   // N/4
{
#pragma clang fp contract(off)
    int tid = blockIdx.x * blockDim.x + threadIdx.x;
    if (tid >= nQuads) return;

    const float R0  = Rp[0];
    const float eta = n1p[0] / n2p[0];
    const float Cx  = Z0f + R0;

    const float4* P4 = (const float4*)P;
    const float4* V4 = (const float4*)V;

    // 4 rays = 12 floats = 3 float4 (fully coalesced 16B/lane loads)
    float4 pa = P4[tid * 3 + 0];
    float4 pb = P4[tid * 3 + 1];
    float4 pc = P4[tid * 3 + 2];
    float4 va = V4[tid * 3 + 0];
    float4 vb = V4[tid * 3 + 1];
    float4 vc = V4[tid * 3 + 2];

    float px[4] = {pa.x, pa.w, pb.z, pc.y};
    float py[4] = {pa.y, pb.x, pb.w, pc.z};
    float pz[4] = {pa.z, pb.y, pc.x, pc.w};
    float vx[4] = {va.x, va.w, vb.z, vc.y};
    float vy[4] = {va.y, vb.x, vb.w, vc.z};
    float vz[4] = {va.z, vb.y, vc.x, vc.w};

    float4 o[6];
    float* of = (float*)o;

    #pragma unroll
    for (int k = 0; k < 4; ++k) {
        // mirror numpy op order exactly; contract(off) forbids fma fusion
        float PCx = px[k] - Cx;
        float PCy = py[k];
        float PCz = pz[k];
        float b = 2.0f * (vx[k]*PCx + vy[k]*PCy + vz[k]*PCz);
        float c = PCx*PCx + PCy*PCy + PCz*PCz - R0*R0;
        float disc = b*b - 4.0f*c;
        float sd = sqrtf(fmaxf(disc, 0.0f));
        float t1 = (-b - sd) * 0.5f;
        float t2 = (-b + sd) * 0.5f;
        float t  = (t1 > EPSf) ? t1 : t2;
        bool hit = (disc >= 0.0f) && (t > EPSf);

        float ptx = px[k] + t * vx[k];
        float pty = py[k] + t * vy[k];
        float ptz = pz[k] + t * vz[k];
        float r2  = pty*pty + ptz*ptz;
        hit = hit && (r2 <= APER2);

        float nx = (ptx - Cx) / R0;
        float ny = pty / R0;
        float nz = ptz / R0;
        float ndotv = nx*vx[k] + ny*vy[k] + nz*vz[k];
        if (ndotv > 0.0f) { nx = -nx; ny = -ny; nz = -nz; }

        float cosi  = -(nx*vx[k] + ny*vy[k] + nz*vz[k]);
        float sin2t = eta*eta*(1.0f - cosi*cosi);
        bool  r_ok  = (sin2t <= 1.0f);
        float cost  = sqrtf(fmaxf(1.0f - sin2t, 0.0f));
        float f     = eta*cosi - cost;
        float Tx = eta*vx[k] + f*nx;
        float Ty = eta*vy[k] + f*ny;
        float Tz = eta*vz[k] + f*nz;

        bool valid = hit && r_ok;
        of[k*6+0] = valid ? ptx : 0.0f;
        of[k*6+1] = valid ? pty : 0.0f;
        of[k*6+2] = valid ? ptz : 0.0f;
        of[k*6+3] = valid ? Tx  : 0.0f;
        of[k*6+4] = valid ? Ty  : 0.0f;
        of[k*6+5] = valid ? Tz  : 0.0f;
    }

    // 4 rays * 6 floats = 24 floats = 6 float4 stores
    float4* O4 = (float4*)out;
    #pragma unroll
    for (int k = 0; k < 6; ++k) O4[tid * 6 + k] = o[k];
}

extern "C" void kernel_launch(void* const* d_in, const int* in_sizes, int n_in,
                              void* d_out, int out_size, void* d_ws, size_t ws_size,
                              hipStream_t stream) {
    const float* P   = (const float*)d_in[0];
    const float* V   = (const float*)d_in[1];
    const float* Rp  = (const float*)d_in[2];
    const float* n1p = (const float*)d_in[3];
    const float* n2p = (const float*)d_in[4];
    float* out = (float*)d_out;

    int n = in_sizes[0] / 3;        // number of rays
    int nQuads = n / 4;             // N = 2^23, divisible by 4
    int block = 256;
    int grid = (nQuads + block - 1) / block;

    refract_kernel<<<grid, block, 0, stream>>>(P, V, Rp, n1p, n2p, out, nQuads);
}

// Round 3
// 77.490 us; speedup vs baseline: 1.4854x; 1.4854x over previous
//
#include <hip/hip_runtime.h>

#pragma clang fp contract(off)

#define Z0f   10.0f
#define EPSf  1e-6f
#define APER2 400.0f   // (DIAMETER/2)^2 = 20^2

// 256 threads/block, 4 rays/thread -> 1024 rays/block.
// All global memory instructions are wave-contiguous (64 lanes x 16B);
// the AoS[N,3] <-> per-ray transpose happens in LDS.
__global__ __launch_bounds__(256) void refract_kernel(
    const float* __restrict__ P,
    const float* __restrict__ V,
    const float* __restrict__ Rp,
    const float* __restrict__ n1p,
    const float* __restrict__ n2p,
    float* __restrict__ out)
{
#pragma clang fp contract(off)
    __shared__ float4 lds[1536];            // 24 KB, reused in+out
    const int t   = threadIdx.x;
    const int blk = blockIdx.x;

    const float R0  = Rp[0];
    const float eta = n1p[0] / n2p[0];
    const float Cx  = Z0f + R0;

    const float4* P4 = (const float4*)P + (size_t)blk * 768;
    const float4* V4 = (const float4*)V + (size_t)blk * 768;

    // ---- stage in: coalesced global loads -> linear LDS (conflict-free) ----
    float4 sp0 = P4[0*256 + t];
    float4 sp1 = P4[1*256 + t];
    float4 sp2 = P4[2*256 + t];
    float4 sv0 = V4[0*256 + t];
    float4 sv1 = V4[1*256 + t];
    float4 sv2 = V4[2*256 + t];
    lds[0*256 + t] = sp0;
    lds[1*256 + t] = sp1;
    lds[2*256 + t] = sp2;
    lds[768 + 0*256 + t] = sv0;
    lds[768 + 1*256 + t] = sv1;
    lds[768 + 2*256 + t] = sv2;
    __syncthreads();

    // ---- per-ray fragment reads (stride-3 float4, ~8-way, cheap in LDS) ----
    float4 pa = lds[3*t + 0];
    float4 pb = lds[3*t + 1];
    float4 pc = lds[3*t + 2];
    float4 va = lds[768 + 3*t + 0];
    float4 vb = lds[768 + 3*t + 1];
    float4 vc = lds[768 + 3*t + 2];
    __syncthreads();   // before overwriting lds with outputs

    float px[4] = {pa.x, pa.w, pb.z, pc.y};
    float py[4] = {pa.y, pb.x, pb.w, pc.z};
    float pz[4] = {pa.z, pb.y, pc.x, pc.w};
    float vx[4] = {va.x, va.w, vb.z, vc.y};
    float vy[4] = {va.y, vb.x, vb.w, vc.z};
    float vz[4] = {va.z, vb.y, vc.x, vc.w};

    float4 o[6];
    float* of = (float*)o;

    #pragma unroll
    for (int k = 0; k < 4; ++k) {
        // mirror numpy op order exactly; contract(off) forbids fma fusion
        float PCx = px[k] - Cx;
        float PCy = py[k];
        float PCz = pz[k];
        float b = 2.0f * (vx[k]*PCx + vy[k]*PCy + vz[k]*PCz);
        float c = PCx*PCx + PCy*PCy + PCz*PCz - R0*R0;
        float disc = b*b - 4.0f*c;
        float sd = sqrtf(fmaxf(disc, 0.0f));
        float t1 = (-b - sd) * 0.5f;
        float t2 = (-b + sd) * 0.5f;
        float tt = (t1 > EPSf) ? t1 : t2;
        bool hit = (disc >= 0.0f) && (tt > EPSf);

        float ptx = px[k] + tt * vx[k];
        float pty = py[k] + tt * vy[k];
        float ptz = pz[k] + tt * vz[k];
        float r2  = pty*pty + ptz*ptz;
        hit = hit && (r2 <= APER2);

        float nx = (ptx - Cx) / R0;
        float ny = pty / R0;
        float nz = ptz / R0;
        float ndotv = nx*vx[k] + ny*vy[k] + nz*vz[k];
        if (ndotv > 0.0f) { nx = -nx; ny = -ny; nz = -nz; }

        float cosi  = -(nx*vx[k] + ny*vy[k] + nz*vz[k]);
        float sin2t = eta*eta*(1.0f - cosi*cosi);
        bool  r_ok  = (sin2t <= 1.0f);
        float cost  = sqrtf(fmaxf(1.0f - sin2t, 0.0f));
        float f     = eta*cosi - cost;
        float Tx = eta*vx[k] + f*nx;
        float Ty = eta*vy[k] + f*ny;
        float Tz = eta*vz[k] + f*nz;

        bool valid = hit && r_ok;
        of[k*6+0] = valid ? ptx : 0.0f;
        of[k*6+1] = valid ? pty : 0.0f;
        of[k*6+2] = valid ? ptz : 0.0f;
        of[k*6+3] = valid ? Tx  : 0.0f;
        of[k*6+4] = valid ? Ty  : 0.0f;
        of[k*6+5] = valid ? Tz  : 0.0f;
    }

    // ---- stage out: SoA LDS write (conflict-free) ----
    // thread t's s-th output float4 == block-local out float4 index 6t+s
    #pragma unroll
    for (int s = 0; s < 6; ++s) lds[s*256 + t] = o[s];
    __syncthreads();

    // ---- streamed coalesced global stores ----
    float4* O4 = (float4*)out + (size_t)blk * 1536;
    #pragma unroll
    for (int k = 0; k < 6; ++k) {
        int j  = k*256 + t;          // block-local out float4 index
        int to = j / 6;              // owner thread
        int s  = j - 6*to;           // slot
        O4[j] = lds[s*256 + to];
    }
}

extern "C" void kernel_launch(void* const* d_in, const int* in_sizes, int n_in,
                              void* d_out, int out_size, void* d_ws, size_t ws_size,
                              hipStream_t stream) {
    const float* P   = (const float*)d_in[0];
    const float* V   = (const float*)d_in[1];
    const float* Rp  = (const float*)d_in[2];
    const float* n1p = (const float*)d_in[3];
    const float* n2p = (const float*)d_in[4];
    float* out = (float*)d_out;

    int n = in_sizes[0] / 3;        // number of rays (2^23)
    int raysPerBlock = 1024;
    int grid = n / raysPerBlock;    // 8192 blocks

    refract_kernel<<<grid, 256, 0, stream>>>(P, V, Rp, n1p, n2p, out);
}

// Round 4
// 75.859 us; speedup vs baseline: 1.5174x; 1.0215x over previous
//
#include <hip/hip_runtime.h>

#pragma clang fp contract(off)

#define Z0f   10.0f
#define EPSf  1e-6f
#define APER2 400.0f   // (DIAMETER/2)^2 = 20^2

// 256 threads/block, 2 rays/thread -> 512 rays/block, 12 KB LDS.
// 12 KB/block => 8 blocks/CU => 32 waves/CU = 100% occupancy.
// All global memory instructions are wave-contiguous; the AoS[N,3] <-> per-ray
// transpose (in) and per-ray -> [N,6] stream (out) happen in LDS.
__global__ __launch_bounds__(256) void refract_kernel(
    const float* __restrict__ P,
    const float* __restrict__ V,
    const float* __restrict__ Rp,
    const float* __restrict__ n1p,
    const float* __restrict__ n2p,
    float* __restrict__ out)
{
#pragma clang fp contract(off)
    __shared__ float4 lds4[768];            // 12 KB, reused in+out
    float2* lds2 = (float2*)lds4;
    float*  ldsf = (float*)lds4;

    const int t   = threadIdx.x;
    const int blk = blockIdx.x;

    const float R0  = Rp[0];
    const float eta = n1p[0] / n2p[0];
    const float Cx  = Z0f + R0;

    // ---- stage in: coalesced float2 loads -> linear LDS (conflict-free) ----
    // block's P chunk: 512 rays * 3 floats = 1536 floats = 768 float2
    const float2* P2 = (const float2*)P + (size_t)blk * 768;
    const float2* V2 = (const float2*)V + (size_t)blk * 768;
    #pragma unroll
    for (int j = 0; j < 3; ++j) {
        lds2[      j*256 + t] = P2[j*256 + t];
        lds2[768 + j*256 + t] = V2[j*256 + t];
    }
    __syncthreads();

    // ---- per-ray reads: thread t owns rays 2t, 2t+1 (floats 6t..6t+5) ----
    float px[2], py[2], pz[2], vx[2], vy[2], vz[2];
    #pragma unroll
    for (int k = 0; k < 2; ++k) {
        px[k] = ldsf[6*t + 3*k + 0];
        py[k] = ldsf[6*t + 3*k + 1];
        pz[k] = ldsf[6*t + 3*k + 2];
        vx[k] = ldsf[1536 + 6*t + 3*k + 0];
        vy[k] = ldsf[1536 + 6*t + 3*k + 1];
        vz[k] = ldsf[1536 + 6*t + 3*k + 2];
    }
    __syncthreads();   // before overwriting lds with outputs

    float4 o[3];
    float* of = (float*)o;

    #pragma unroll
    for (int k = 0; k < 2; ++k) {
        // mirror numpy op order exactly; contract(off) forbids fma fusion
        float PCx = px[k] - Cx;
        float PCy = py[k];
        float PCz = pz[k];
        float b = 2.0f * (vx[k]*PCx + vy[k]*PCy + vz[k]*PCz);
        float c = PCx*PCx + PCy*PCy + PCz*PCz - R0*R0;
        float disc = b*b - 4.0f*c;
        float sd = sqrtf(fmaxf(disc, 0.0f));
        float t1 = (-b - sd) * 0.5f;
        float t2 = (-b + sd) * 0.5f;
        float tt = (t1 > EPSf) ? t1 : t2;
        bool hit = (disc >= 0.0f) && (tt > EPSf);

        float ptx = px[k] + tt * vx[k];
        float pty = py[k] + tt * vy[k];
        float ptz = pz[k] + tt * vz[k];
        float r2  = pty*pty + ptz*ptz;
        hit = hit && (r2 <= APER2);

        float nx = (ptx - Cx) / R0;
        float ny = pty / R0;
        float nz = ptz / R0;
        float ndotv = nx*vx[k] + ny*vy[k] + nz*vz[k];
        if (ndotv > 0.0f) { nx = -nx; ny = -ny; nz = -nz; }

        float cosi  = -(nx*vx[k] + ny*vy[k] + nz*vz[k]);
        float sin2t = eta*eta*(1.0f - cosi*cosi);
        bool  r_ok  = (sin2t <= 1.0f);
        float cost  = sqrtf(fmaxf(1.0f - sin2t, 0.0f));
        float f     = eta*cosi - cost;
        float Tx = eta*vx[k] + f*nx;
        float Ty = eta*vy[k] + f*ny;
        float Tz = eta*vz[k] + f*nz;

        bool valid = hit && r_ok;
        of[k*6+0] = valid ? ptx : 0.0f;
        of[k*6+1] = valid ? pty : 0.0f;
        of[k*6+2] = valid ? ptz : 0.0f;
        of[k*6+3] = valid ? Tx  : 0.0f;
        of[k*6+4] = valid ? Ty  : 0.0f;
        of[k*6+5] = valid ? Tz  : 0.0f;
    }

    // ---- stage out: thread t's 12 floats -> lds4[s*256+t], s=0..2 ----
    #pragma unroll
    for (int s = 0; s < 3; ++s) lds4[s*256 + t] = o[s];
    __syncthreads();

    // ---- streamed coalesced global stores ----
    // block out = 512 rays * 6 floats = 768 float4; owner of out-float4 j is
    // thread j/3, slot j%3 (thread to's slot s = block floats 12*to + 4*s).
    float4* O4 = (float4*)out + (size_t)blk * 768;
    #pragma unroll
    for (int k = 0; k < 3; ++k) {
        int j  = k*256 + t;
        int to = j / 3;
        int s  = j - 3*to;
        O4[j] = lds4[s*256 + to];
    }
}

extern "C" void kernel_launch(void* const* d_in, const int* in_sizes, int n_in,
                              void* d_out, int out_size, void* d_ws, size_t ws_size,
                              hipStream_t stream) {
    const float* P   = (const float*)d_in[0];
    const float* V   = (const float*)d_in[1];
    const float* Rp  = (const float*)d_in[2];
    const float* n1p = (const float*)d_in[3];
    const float* n2p = (const float*)d_in[4];
    float* out = (float*)d_out;

    int n = in_sizes[0] / 3;        // number of rays (2^23)
    int raysPerBlock = 512;
    int grid = n / raysPerBlock;    // 16384 blocks

    refract_kernel<<<grid, 256, 0, stream>>>(P, V, Rp, n1p, n2p, out);
}

// Round 6
// 61.843 us; speedup vs baseline: 1.8613x; 1.2266x over previous
//
#include <hip/hip_runtime.h>

#pragma clang fp contract(off)

#define Z0f   10.0f
#define EPSf  1e-6f
#define APER2 400.0f   // (DIAMETER/2)^2 = 20^2

typedef float f32x4 __attribute__((ext_vector_type(4)));

// 256 threads/block, 2 rays/thread -> 512 rays/block, 12 KB LDS.
// All global memory instructions are wave-contiguous; AoS transpose in LDS.
// Hit-determining math (b,c,disc,t,pts,r2) mirrors numpy bitwise
// (contract(off), exact op order). Normal/refraction path uses *invR
// (<=2 ulp from /R0; feeds only continuous outputs, no predicate risk).
__global__ __launch_bounds__(256) void refract_kernel(
    const float* __restrict__ P,
    const float* __restrict__ V,
    const float* __restrict__ Rp,
    const float* __restrict__ n1p,
    const float* __restrict__ n2p,
    float* __restrict__ out)
{
#pragma clang fp contract(off)
    __shared__ f32x4 lds4[768];             // 12 KB, reused in+out
    float2* lds2 = (float2*)lds4;
    float*  ldsf = (float*)lds4;

    const int t   = threadIdx.x;
    const int blk = blockIdx.x;

    const float R0   = Rp[0];
    const float eta  = n1p[0] / n2p[0];
    const float Cx   = Z0f + R0;
    const float invR = 1.0f / R0;

    // ---- stage in: coalesced float2 loads -> linear LDS (conflict-free) ----
    const float2* P2 = (const float2*)P + (size_t)blk * 768;
    const float2* V2 = (const float2*)V + (size_t)blk * 768;
    #pragma unroll
    for (int j = 0; j < 3; ++j) {
        lds2[      j*256 + t] = P2[j*256 + t];
        lds2[768 + j*256 + t] = V2[j*256 + t];
    }
    __syncthreads();

    // ---- per-ray reads: thread t owns rays 2t, 2t+1 ----
    float px[2], py[2], pz[2], vx[2], vy[2], vz[2];
    #pragma unroll
    for (int k = 0; k < 2; ++k) {
        px[k] = ldsf[6*t + 3*k + 0];
        py[k] = ldsf[6*t + 3*k + 1];
        pz[k] = ldsf[6*t + 3*k + 2];
        vx[k] = ldsf[1536 + 6*t + 3*k + 0];
        vy[k] = ldsf[1536 + 6*t + 3*k + 1];
        vz[k] = ldsf[1536 + 6*t + 3*k + 2];
    }
    __syncthreads();   // before overwriting lds with outputs

    f32x4 o[3];
    float* of = (float*)o;

    #pragma unroll
    for (int k = 0; k < 2; ++k) {
        // hit chain: numpy op order exactly, no fma
        float PCx = px[k] - Cx;
        float PCy = py[k];
        float PCz = pz[k];
        float b = 2.0f * (vx[k]*PCx + vy[k]*PCy + vz[k]*PCz);
        float c = PCx*PCx + PCy*PCy + PCz*PCz - R0*R0;
        float disc = b*b - 4.0f*c;
        float sd = sqrtf(fmaxf(disc, 0.0f));
        float t1 = (-b - sd) * 0.5f;
        float t2 = (-b + sd) * 0.5f;
        float tt = (t1 > EPSf) ? t1 : t2;
        bool hit = (disc >= 0.0f) && (tt > EPSf);

        float ptx = px[k] + tt * vx[k];
        float pty = py[k] + tt * vy[k];
        float ptz = pz[k] + tt * vz[k];
        float r2  = pty*pty + ptz*ptz;
        hit = hit && (r2 <= APER2);

        // continuous-only path: reciprocal-multiply instead of IEEE divide
        float nx = (ptx - Cx) * invR;
        float ny = pty * invR;
        float nz = ptz * invR;
        float ndotv = nx*vx[k] + ny*vy[k] + nz*vz[k];
        if (ndotv > 0.0f) { nx = -nx; ny = -ny; nz = -nz; }

        float cosi  = -(nx*vx[k] + ny*vy[k] + nz*vz[k]);
        float sin2t = eta*eta*(1.0f - cosi*cosi);
        bool  r_ok  = (sin2t <= 1.0f);
        float cost  = sqrtf(fmaxf(1.0f - sin2t, 0.0f));
        float f     = eta*cosi - cost;
        float Tx = eta*vx[k] + f*nx;
        float Ty = eta*vy[k] + f*ny;
        float Tz = eta*vz[k] + f*nz;

        bool valid = hit && r_ok;
        of[k*6+0] = valid ? ptx : 0.0f;
        of[k*6+1] = valid ? pty : 0.0f;
        of[k*6+2] = valid ? ptz : 0.0f;
        of[k*6+3] = valid ? Tx  : 0.0f;
        of[k*6+4] = valid ? Ty  : 0.0f;
        of[k*6+5] = valid ? Tz  : 0.0f;
    }

    // ---- stage out: thread t's 12 floats -> lds4[s*256+t], s=0..2 ----
    #pragma unroll
    for (int s = 0; s < 3; ++s) lds4[s*256 + t] = o[s];
    __syncthreads();

    // ---- streamed coalesced non-temporal global stores ----
    f32x4* O4 = (f32x4*)out + (size_t)blk * 768;
    #pragma unroll
    for (int k = 0; k < 3; ++k) {
        int j  = k*256 + t;
        int to = j / 3;
        int s  = j - 3*to;
        __builtin_nontemporal_store(lds4[s*256 + to], &O4[j]);
    }
}

extern "C" void kernel_launch(void* const* d_in, const int* in_sizes, int n_in,
                              void* d_out, int out_size, void* d_ws, size_t ws_size,
                              hipStream_t stream) {
    const float* P   = (const float*)d_in[0];
    const float* V   = (const float*)d_in[1];
    const float* Rp  = (const float*)d_in[2];
    const float* n1p = (const float*)d_in[3];
    const float* n2p = (const float*)d_in[4];
    float* out = (float*)d_out;

    int n = in_sizes[0] / 3;        // number of rays (2^23)
    int raysPerBlock = 512;
    int grid = n / raysPerBlock;    // 16384 blocks

    refract_kernel<<<grid, 256, 0, stream>>>(P, V, Rp, n1p, n2p, out);
}